// Round 11
// baseline (49.429 us; speedup 1.0000x reference)
//
#include <hip/hip_runtime.h>

#define EMBED 512
#define NTOK 8192
#define MT 16            // tokens per block (one MFMA M-tile)
#define NB1 6            // GEMM1 N-fragments (96 cols = 16 h | 64 W1 | 4 xb | pad)
#define KS1 16           // GEMM1 K-steps (512/32)
#define NB2 32           // GEMM2 N-fragments (512 cols)
#define KS2 3            // GEMM2 K-steps (96/32; rows 68..95 zero)
#define ZR 104           // LDS z row pitch (halves)

using half8   = __attribute__((ext_vector_type(8))) _Float16;
using half2_t = __attribute__((ext_vector_type(2))) _Float16;
using f32x4   = __attribute__((ext_vector_type(4))) float;
using uint4_t = __attribute__((ext_vector_type(4))) unsigned;

#define MFMA16(a, b, c) __builtin_amdgcn_mfma_f32_16x16x32_f16((a), (b), (c), 0, 0, 0)

__device__ __forceinline__ unsigned pkrtz_u(float a, float b) {
    return __builtin_bit_cast(unsigned, __builtin_amdgcn_cvt_pkrtz(a, b));
}
__device__ __forceinline__ half2_t pkrtz(float a, float b) {
    return __builtin_bit_cast(half2_t, __builtin_amdgcn_cvt_pkrtz(a, b));
}
__device__ __forceinline__ half8 pack8(float4 a0, float4 a1) {
    uint4_t u;
    u.x = pkrtz_u(a0.x, a0.y);
    u.y = pkrtz_u(a0.z, a0.w);
    u.z = pkrtz_u(a1.x, a1.y);
    u.w = pkrtz_u(a1.z, a1.w);
    return __builtin_bit_cast(half8, u);
}
__device__ __forceinline__ half8 cvt8(const float* v) {
    half8 h;
    #pragma unroll
    for (int i = 0; i < 8; ++i) h[i] = (_Float16)v[i];   // RNE
    return h;
}

// ---------------------------------------------------------------------------
// ONE kernel, no prep, no workspace. Per 16-token block (8 waves):
//  - waves 0-5 build their B1 fragment column in-register from raw weights
//  - GEMM1 A-frags stream straight from global x (f32 -> pkrtz), no LDS stage
//  - glue on wave 0; all waves build B2 frags in-register (contiguous reads)
//  - GEMM2 from registers; relu store.
// B-frag convention: frag(ks,nf): lane l holds B[k=ks*32+(l>>4)*8+i][col=nf*16+(l&15)]
// A-frag: lane l holds A[row=l&15][k=(l>>4)*8+i]; C: [row=(l>>4)*4+r][col=l&15]
// ---------------------------------------------------------------------------
__global__ __launch_bounds__(512, 2) void hyper(const float* __restrict__ x,
                                                const float* __restrict__ fc1w,
                                                const float* __restrict__ fc1b,
                                                const float* __restrict__ fc2w,
                                                const float* __restrict__ fc2b,
                                                float* __restrict__ out)
{
    __shared__ float    c1s[MT][100];       // 6.4 KB GEMM1 result spill
    __shared__ _Float16 zh[MT][ZR];         // 3.3 KB Z (f16)

    const int tid  = threadIdx.x;
    const int lane = tid & 63;
    const int wv   = tid >> 6;              // 0..7
    const int rowA = lane & 15;
    const int kgrp = lane >> 4;             // 0..3
    const long tok0 = (long)blockIdx.x * MT;
    const bool hasG1 = (wv < 6);

    // ---- build B1 frag column nf = wv in registers (waves 0-5) --------------
    half8 b1a[KS1];
    if (wv == 0) {
        // cols 0-15: fc1w^T  -> B[e][c] = fc1w[c*512+e], 8 contiguous e
        #pragma unroll
        for (int ks = 0; ks < KS1; ++ks) {
            const float4* p = reinterpret_cast<const float4*>(
                fc1w + rowA * EMBED + ks * 32 + kgrp * 8);
            float4 a = p[0], b = p[1];
            float v[8] = {a.x, a.y, a.z, a.w, b.x, b.y, b.z, b.w};
            b1a[ks] = cvt8(v);
        }
    } else if (wv <= 4) {
        // cols 16-79: W1[e][j][kh] = fc2w[e*64 + j*16 + kh]
        const int j = wv - 1, kh = rowA;
        #pragma unroll
        for (int ks = 0; ks < KS1; ++ks) {
            const int k0 = ks * 32 + kgrp * 8;
            const float* p = fc2w + (long)k0 * 64 + j * 16 + kh;
            float v[8];
            #pragma unroll
            for (int i = 0; i < 8; ++i) v[i] = p[i * 64];
            b1a[ks] = cvt8(v);
        }
    } else if (wv == 5) {
        // cols 80-83: b1[e][j] = fc2b[e*4+j]; cols 84-95: zero
        #pragma unroll
        for (int ks = 0; ks < KS1; ++ks) {
            const int k0 = ks * 32 + kgrp * 8;
            float v[8];
            #pragma unroll
            for (int i = 0; i < 8; ++i)
                v[i] = (rowA < 4) ? fc2b[(k0 + i) * 4 + rowA] : 0.f;
            b1a[ks] = cvt8(v);
        }
    }

    // ================= GEMM1: X[16x512] * B1[512x96], A from global ==========
    f32x4 accA = {0.f, 0.f, 0.f, 0.f};
    if (hasG1) {
        #pragma unroll
        for (int ks = 0; ks < KS1; ++ks) {
            const float4* xp = reinterpret_cast<const float4*>(
                x + (tok0 + rowA) * EMBED + ks * 32 + kgrp * 8);
            float4 a0 = xp[0], a1 = xp[1];
            accA = MFMA16(pack8(a0, a1), b1a[ks], accA);
        }
        #pragma unroll
        for (int r = 0; r < 4; ++r) c1s[kgrp * 4 + r][wv * 16 + rowA] = accA[r];
    }

    // ---- build B2 frags in registers (4 per wave); hides under barrier+glue -
    half8 b2r[KS2][4];
    #pragma unroll
    for (int f = 0; f < 4; ++f) {
        const int e = (wv * 4 + f) * 16 + rowA;
        // ks 0,1: rows j*16+kh -> W2[j][e][kh] = fc2w[(2048 + j*512 + e)*16 + kh]
        #pragma unroll
        for (int ks = 0; ks < 2; ++ks) {
            const int k0 = ks * 32 + kgrp * 8;           // k0&15 in {0,8}
            const float4* p = reinterpret_cast<const float4*>(
                fc2w + (long)(2048 + (k0 >> 4) * 512 + e) * 16 + (k0 & 15));
            float4 a = p[0], b = p[1];
            float v[8] = {a.x, a.y, a.z, a.w, b.x, b.y, b.z, b.w};
            b2r[ks][f] = cvt8(v);
        }
        // ks 2: rows 64-67 = b2[j][e]; 68+ zero
        {
            float v[8];
            #pragma unroll
            for (int i = 0; i < 8; ++i) {
                const int krow = 64 + kgrp * 8 + i;
                v[i] = (krow < 68) ? fc2b[2048 + (krow - 64) * 512 + e] : 0.f;
            }
            b2r[2][f] = cvt8(v);
        }
    }

    __syncthreads();

    // ================= glue: h, y1, Z = (y1 (x) h | y1 | 0) ==================
    if (tid < 64) {
        const int t = tid & 15, j = tid >> 4;
        float h[16];
        #pragma unroll
        for (int k = 0; k < 16; ++k) h[k] = fmaxf(c1s[t][k] + fc1b[k], 0.f);
        float y1 = c1s[t][80 + j];
        #pragma unroll
        for (int k = 0; k < 16; ++k) y1 = fmaf(c1s[t][16 + j * 16 + k], h[k], y1);
        y1 = fmaxf(y1, 0.f);
        #pragma unroll
        for (int k = 0; k < 16; k += 2) {
            half2_t p = pkrtz(y1 * h[k], y1 * h[k + 1]);
            *reinterpret_cast<half2_t*>(&zh[t][j * 16 + k]) = p;
        }
        zh[t][64 + j] = (_Float16)y1;
        #pragma unroll
        for (int p = 0; p < 7; ++p) zh[t][68 + j * 7 + p] = (_Float16)0.f;
    }
    __syncthreads();

    // ================= GEMM2: Z[16x96] * B2[96x512], B in regs ===============
    f32x4 acc2[4];
    #pragma unroll
    for (int f = 0; f < 4; ++f) acc2[f] = (f32x4){0.f, 0.f, 0.f, 0.f};

    #pragma unroll
    for (int ks = 0; ks < KS2; ++ks) {
        half8 az = *reinterpret_cast<const half8*>(&zh[rowA][ks * 32 + kgrp * 8]);
        #pragma unroll
        for (int f = 0; f < 4; ++f) acc2[f] = MFMA16(az, b2r[ks][f], acc2[f]);
    }

    // ================= relu + store ==========================================
    #pragma unroll
    for (int f = 0; f < 4; ++f) {
        const int e = (wv * 4 + f) * 16 + rowA;
        #pragma unroll
        for (int r = 0; r < 4; ++r) {
            out[(tok0 + kgrp * 4 + r) * EMBED + e] = fmaxf(acc2[f][r], 0.f);
        }
    }
}

extern "C" void kernel_launch(void* const* d_in, const int* in_sizes, int n_in,
                              void* d_out, int out_size, void* d_ws, size_t ws_size,
                              hipStream_t stream) {
    const float* x    = (const float*)d_in[0];
    const float* fc1w = (const float*)d_in[1];
    const float* fc1b = (const float*)d_in[2];
    const float* fc2w = (const float*)d_in[3];
    const float* fc2b = (const float*)d_in[4];
    float* out = (float*)d_out;

    hyper<<<dim3(NTOK / MT), dim3(512), 0, stream>>>(x, fc1w, fc1b, fc2w, fc2b, out);
}

// Round 12
// 19.326 us; speedup vs baseline: 2.5577x; 2.5577x over previous
//
#include <hip/hip_runtime.h>

#define EMBED 512
#define NTOK 8192
#define MT 32            // tokens per block (two 16-row MFMA M-tiles)
#define NB1 6            // GEMM1 N-fragments (96 cols = 16 h | 64 W1 | 4 xb | pad)
#define KS1 16           // GEMM1 K-steps (512/32)
#define NB2 32           // GEMM2 N-fragments (512 cols)
#define KS2 3            // GEMM2 K-steps (96/32; rows 68..95 zero)
#define B1ELEMS (KS1 * NB1 * 64 * 8)   // 49152 halves = 96 KB
#define B2ELEMS (KS2 * NB2 * 64 * 8)   // 49152
#define XR 520           // x LDS pitch (halves): 1040 B == 4 banks mod 32
#define ZR 104           // z LDS pitch (halves): 208 B == 20 banks mod 32

using half8   = __attribute__((ext_vector_type(8))) _Float16;
using half2_t = __attribute__((ext_vector_type(2))) _Float16;
using f32x4   = __attribute__((ext_vector_type(4))) float;

#define MFMA16(a, b, c) __builtin_amdgcn_mfma_f32_16x16x32_f16((a), (b), (c), 0, 0, 0)

__device__ __forceinline__ unsigned pkrtz_u(float a, float b) {
    return __builtin_bit_cast(unsigned, __builtin_amdgcn_cvt_pkrtz(a, b));
}
__device__ __forceinline__ half2_t pkrtz(float a, float b) {
    return __builtin_bit_cast(half2_t, __builtin_amdgcn_cvt_pkrtz(a, b));
}

// ---------------------------------------------------------------------------
// prep (R9, proven): pack B1 [512x96] and B2 [96x512] f16 in MFMA B-frag order.
// frag(ks,nf): lane l holds B[k=ks*32+(l>>4)*8+i][col=nf*16+(l&15)],
// flat [ks][nf][lane][i] -> coalesced 16B/lane loads in main.
// ---------------------------------------------------------------------------
__global__ __launch_bounds__(512) void prep(const float* __restrict__ fc1w,
                                            const float* __restrict__ fc2w,
                                            const float* __restrict__ fc2b,
                                            _Float16* __restrict__ b1f,
                                            _Float16* __restrict__ b2f)
{
    const int g = blockIdx.x * 512 + threadIdx.x;      // 0..12287 slots
    float v[8];
    if (g < B1ELEMS / 8) {
        const int lane = g & 63, rest = g >> 6;
        const int nf = rest % NB1, kstep = rest / NB1;
        const int k0 = kstep * 32 + ((lane >> 4) << 3);
        const int c  = nf * 16 + (lane & 15);
        if (c < 16) {
            const float4* p = reinterpret_cast<const float4*>(fc1w + c * EMBED + k0);
            float4 a = p[0], b = p[1];
            v[0]=a.x; v[1]=a.y; v[2]=a.z; v[3]=a.w; v[4]=b.x; v[5]=b.y; v[6]=b.z; v[7]=b.w;
        } else if (c < 80) {
            const int cc = c - 16;
            const float* p = fc2w + k0 * 64 + (cc >> 4) * 16 + (cc & 15);
            #pragma unroll
            for (int i = 0; i < 8; ++i) v[i] = p[i * 64];
        } else if (c < 84) {
            const float* p = fc2b + k0 * 4 + (c - 80);
            #pragma unroll
            for (int i = 0; i < 8; ++i) v[i] = p[i * 4];
        } else {
            #pragma unroll
            for (int i = 0; i < 8; ++i) v[i] = 0.f;
        }
        half8 h;
        #pragma unroll
        for (int i = 0; i < 8; ++i) h[i] = (_Float16)v[i];
        *reinterpret_cast<half8*>(b1f + g * 8) = h;
    } else if (g < (B1ELEMS + B2ELEMS) / 8) {
        const int g2 = g - B1ELEMS / 8;
        const int lane = g2 & 63, rest = g2 >> 6;
        const int nf = rest & 31, kstep = rest >> 5;
        const int k0 = kstep * 32 + ((lane >> 4) << 3);
        const int e  = nf * 16 + (lane & 15);
        if (k0 < 64) {
            const float4* p = reinterpret_cast<const float4*>(
                fc2w + (2048 + (k0 >> 4) * 512 + e) * 16 + (k0 & 15));
            float4 a = p[0], b = p[1];
            v[0]=a.x; v[1]=a.y; v[2]=a.z; v[3]=a.w; v[4]=b.x; v[5]=b.y; v[6]=b.z; v[7]=b.w;
        } else if (k0 == 64) {
            #pragma unroll
            for (int i = 0; i < 8; ++i)
                v[i] = (i < 4) ? fc2b[2048 + i * 512 + e] : 0.f;
        } else {
            #pragma unroll
            for (int i = 0; i < 8; ++i) v[i] = 0.f;
        }
        half8 h;
        #pragma unroll
        for (int i = 0; i < 8; ++i) h[i] = (_Float16)v[i];
        *reinterpret_cast<half8*>(b2f + g2 * 8) = h;
    }
}

// ---------------------------------------------------------------------------
// main: MT=32 tokens/block, 256 blocks (1/CU), 8 waves. B1 panel staged to LDS
// once (block-invariant); b2 frags in 48 regs; single streaming pass:
//   issue x+b1 loads -> stage LDS -> GEMM1(LDS) -> b2 prefetch -> glue ->
//   GEMM2 -> store. Peak ~120 VGPR: no spills.
// ---------------------------------------------------------------------------
__global__ __launch_bounds__(512, 2) void hyper(const float* __restrict__ x,
                                                const float* __restrict__ fc1b,
                                                const _Float16* __restrict__ b1f,
                                                const _Float16* __restrict__ b2f,
                                                float* __restrict__ out)
{
    __shared__ _Float16 b1lds[B1ELEMS];     // 96 KB
    __shared__ _Float16 xh[MT][XR];         // 33.3 KB
    __shared__ float    c1s[MT][100];       // 12.8 KB
    __shared__ _Float16 zh[MT][ZR];         // 6.7 KB  -> total 148.8 KB

    const int tid  = threadIdx.x;
    const int lane = tid & 63;
    const int wv   = tid >> 6;              // 0..7
    const int rowA = lane & 15;
    const int kgrp = lane >> 4;             // 0..3
    const long tok0 = (long)blockIdx.x * MT;

    // ---- issue x loads (64 KB HBM) and b1 loads (96 KB L2) together ---------
    float4 xr[8];
    {
        const float4* xg = reinterpret_cast<const float4*>(x + tok0 * EMBED);
        #pragma unroll
        for (int i = 0; i < 8; ++i) xr[i] = xg[tid + i * 512];
    }
    half8 b1r[12];
    #pragma unroll
    for (int i = 0; i < 12; ++i)
        b1r[i] = *reinterpret_cast<const half8*>(b1f + (i * 512 + tid) * 8);

    // ---- x -> f16 LDS; b1 -> LDS (both coalesced, 2-way max conflicts) ------
    #pragma unroll
    for (int i = 0; i < 8; ++i) {
        const int idx = tid + i * 512;                // 4096 float4
        const int t = idx >> 7, e4 = idx & 127;
        uint2 w;
        w.x = pkrtz_u(xr[i].x, xr[i].y);
        w.y = pkrtz_u(xr[i].z, xr[i].w);
        *reinterpret_cast<uint2*>(&xh[t][e4 * 4]) = w;
    }
    #pragma unroll
    for (int i = 0; i < 12; ++i)
        *reinterpret_cast<half8*>(&b1lds[(i * 512 + tid) * 8]) = b1r[i];

    __syncthreads();

    // ================= GEMM1: X[32x512] * B1[512x96] (waves 0-5) =============
    if (wv < 6) {
        const int nfp = wv >> 1, mt = wv & 1;         // nf pair {2nfp, 2nfp+1}
        const int nf0 = nfp * 2, nf1 = nf0 + 1;
        f32x4 accA = {0.f, 0.f, 0.f, 0.f};
        f32x4 accB = {0.f, 0.f, 0.f, 0.f};
        #pragma unroll
        for (int ks = 0; ks < KS1; ++ks) {
            half8 a  = *reinterpret_cast<const half8*>(&xh[mt * 16 + rowA][ks * 32 + kgrp * 8]);
            half8 b0 = *reinterpret_cast<const half8*>(&b1lds[((ks * NB1 + nf0) * 64 + lane) * 8]);
            half8 b1v = *reinterpret_cast<const half8*>(&b1lds[((ks * NB1 + nf1) * 64 + lane) * 8]);
            accA = MFMA16(a, b0, accA);
            accB = MFMA16(a, b1v, accB);
        }
        #pragma unroll
        for (int r = 0; r < 4; ++r) {
            c1s[mt * 16 + kgrp * 4 + r][nf0 * 16 + rowA] = accA[r];
            c1s[mt * 16 + kgrp * 4 + r][nf1 * 16 + rowA] = accB[r];
        }
    }

    // ---- b2 prefetch: 4 frags/wave (48 VGPR), hides under barrier+glue ------
    half8 b2r[KS2][4];
    #pragma unroll
    for (int ks = 0; ks < KS2; ++ks)
        #pragma unroll
        for (int f = 0; f < 4; ++f)
            b2r[ks][f] = *reinterpret_cast<const half8*>(
                b2f + ((ks * NB2 + wv * 4 + f) * 64 + lane) * 8);

    __syncthreads();

    // ================= glue (tid<128): h, y1, Z = (y1 (x) h | y1 | 0) ========
    if (tid < 128) {
        const int t = tid >> 2, j = tid & 3;
        float h[16];
        #pragma unroll
        for (int k = 0; k < 16; ++k) h[k] = fmaxf(c1s[t][k] + fc1b[k], 0.f);
        float y1 = c1s[t][80 + j];
        #pragma unroll
        for (int k = 0; k < 16; ++k) y1 = fmaf(c1s[t][16 + j * 16 + k], h[k], y1);
        y1 = fmaxf(y1, 0.f);
        #pragma unroll
        for (int k = 0; k < 16; k += 2) {
            half2_t p = pkrtz(y1 * h[k], y1 * h[k + 1]);
            *reinterpret_cast<half2_t*>(&zh[t][j * 16 + k]) = p;
        }
        zh[t][64 + j] = (_Float16)y1;
        #pragma unroll
        for (int p = 0; p < 7; ++p) zh[t][68 + j * 7 + p] = (_Float16)0.f;
    }
    __syncthreads();

    // ================= GEMM2: Z[32x96] * B2[96x512], 2 M-tiles/wave ==========
    f32x4 acc20[4], acc21[4];
    #pragma unroll
    for (int f = 0; f < 4; ++f) {
        acc20[f] = (f32x4){0.f, 0.f, 0.f, 0.f};
        acc21[f] = (f32x4){0.f, 0.f, 0.f, 0.f};
    }
    #pragma unroll
    for (int ks = 0; ks < KS2; ++ks) {
        half8 az0 = *reinterpret_cast<const half8*>(&zh[rowA][ks * 32 + kgrp * 8]);
        half8 az1 = *reinterpret_cast<const half8*>(&zh[16 + rowA][ks * 32 + kgrp * 8]);
        #pragma unroll
        for (int f = 0; f < 4; ++f) {
            acc20[f] = MFMA16(az0, b2r[ks][f], acc20[f]);
            acc21[f] = MFMA16(az1, b2r[ks][f], acc21[f]);
        }
    }

    // ================= relu + store ==========================================
    #pragma unroll
    for (int f = 0; f < 4; ++f) {
        const int e = (wv * 4 + f) * 16 + rowA;
        #pragma unroll
        for (int r = 0; r < 4; ++r) {
            out[(tok0 + kgrp * 4 + r) * EMBED + e]      = fmaxf(acc20[f][r], 0.f);
            out[(tok0 + 16 + kgrp * 4 + r) * EMBED + e] = fmaxf(acc21[f][r], 0.f);
        }
    }
}

extern "C" void kernel_launch(void* const* d_in, const int* in_sizes, int n_in,
                              void* d_out, int out_size, void* d_ws, size_t ws_size,
                              hipStream_t stream) {
    const float* x    = (const float*)d_in[0];
    const float* fc1w = (const float*)d_in[1];
    const float* fc1b = (const float*)d_in[2];
    const float* fc2w = (const float*)d_in[3];
    const float* fc2b = (const float*)d_in[4];
    float* out = (float*)d_out;

    _Float16* b1f = (_Float16*)d_ws;                   // 96 KB
    _Float16* b2f = b1f + B1ELEMS;                     // 96 KB

    prep<<<dim3((B1ELEMS + B2ELEMS) / 8 / 512), dim3(512), 0, stream>>>(fc1w, fc2w, fc2b, b1f, b2f);
    hyper<<<dim3(NTOK / MT), dim3(512), 0, stream>>>(x, fc1b, b1f, b2f, out);
}